// Round 7
// baseline (494.449 us; speedup 1.0000x reference)
//
#include <hip/hip_runtime.h>
#include <cstddef>

// ---------------------------------------------------------------------------
// GNN forward: embed+posenc -> 2x TransformerConv(8 heads x 32) -> 2x GCNConv
// N=50000, E=400000, IN=63, D=32, HC=256.
// R7: Q stored bf16 (natural channel order == per-lane layout); attn
// group-of-8 prefetch (launch_bounds(256,4) to keep buffers in VGPRs);
// GCN feature rows bf16 with both 32x32 GEMMs fused into producer epilogues
// (attn-L2 emits XW3, gcn-L3 emits XW4 via width-32 shuffle matmul).
// No-max softmax; CSR built once; no per-edge atomics anywhere.
// ---------------------------------------------------------------------------

#define NH 8
#define HCH 256
#define D32 32
#define INCH 63
#define CSCALE 0.25503485356f   // log2(e) / sqrt(32)

__device__ __forceinline__ unsigned short f2bf(float f) {
    unsigned u = __float_as_uint(f);
    u += 0x7fff + ((u >> 16) & 1);   // RNE
    return (unsigned short)(u >> 16);
}
__device__ __forceinline__ float bfu(unsigned short u) {
    return __uint_as_float(((unsigned)u) << 16);
}

// inv_freq[j] = 10000^(-2j/32) = 10^(-j/4)
__device__ const float c_invf[16] = {
    1.0f, 0.5623413251903491f, 0.31622776601683794f, 0.17782794100389228f,
    0.1f, 0.05623413251903491f, 0.031622776601683791f, 0.017782794100389228f,
    0.01f, 0.005623413251903491f, 0.0031622776601683794f, 0.0017782794100389228f,
    0.001f, 0.0005623413251903491f, 0.00031622776601683794f, 0.00017782794100389227f
};

// --- embed (+ compose in 2 blocks, + edge-count in trailing blocks) --------
__global__ __launch_bounds__(256) void k_embed(
    const float* __restrict__ x, const float* __restrict__ W,
    const float* __restrict__ b, float* __restrict__ H, int N, int nbMain,
    int E, const int* __restrict__ dst, int* __restrict__ cnt,
    const float* __restrict__ Wsk1, const float* __restrict__ bsk1,
    const float* __restrict__ Wh1,  const float* __restrict__ bh1,
    const float* __restrict__ Wsk2, const float* __restrict__ bsk2,
    const float* __restrict__ Wh2,  const float* __restrict__ bh2,
    float* __restrict__ WCB)
{
    if (blockIdx.x >= nbMain + 2) {
        int e = (blockIdx.x - nbMain - 2) * 256 + threadIdx.x;
        if (e < E) atomicAdd(&cnt[dst[e]], 1);
        return;
    }
    if (blockIdx.x >= nbMain) {
        int lay = blockIdx.x - nbMain;
        const float* Wsk = lay ? Wsk2 : Wsk1;
        const float* bsk = lay ? bsk2 : bsk1;
        const float* Wh  = lay ? Wh2  : Wh1;
        const float* bh  = lay ? bh2  : bh1;
        float* o = WCB + lay * 1056;
        for (int i = threadIdx.x; i < D32 * D32 + D32; i += 256) {
            if (i < D32 * D32) {
                int r = i >> 5, c = i & 31;
                float a = 0.f;
                for (int k = 0; k < HCH; ++k) a = fmaf(Wsk[r * HCH + k], Wh[k * D32 + c], a);
                o[i] = a;
            } else {
                int c = i - D32 * D32;
                float a = bh[c];
                for (int k = 0; k < HCH; ++k) a = fmaf(bsk[k], Wh[k * D32 + c], a);
                o[1024 + c] = a;
            }
        }
        return;
    }
    __shared__ float xs[8][64];
    __shared__ float ws[INCH * D32];
    int row0 = blockIdx.x * 8;
    for (int i = threadIdx.x; i < INCH * D32; i += 256) ws[i] = W[i];
    for (int i = threadIdx.x; i < 8 * INCH; i += 256) {
        int r = i / INCH, cc = i % INCH;
        int gr = row0 + r;
        xs[r][cc] = (gr < N) ? x[(size_t)gr * INCH + cc] : 0.f;
    }
    __syncthreads();
    int lr = threadIdx.x >> 5, c = threadIdx.x & 31;
    int row = row0 + lr;
    if (row >= N) return;
    float acc = b[c];
#pragma unroll
    for (int k = 0; k < INCH; ++k) acc = fmaf(xs[lr][k], ws[k * D32 + c], acc);
    float phase = (float)row * c_invf[c >> 1];
    float pe = (c & 1) ? cosf(phase) : sinf(phase);
    H[(size_t)row * D32 + c] = acc + pe;
}

// --- CSR build -------------------------------------------------------------
__global__ void k_scan1(const int* __restrict__ cnt, int* __restrict__ rowptr,
                        int* __restrict__ partials, float* __restrict__ DIS, int N)
{
    __shared__ int s[256];
    int g = blockIdx.x * 256 + threadIdx.x;
    int myc = (g < N) ? cnt[g] : 0;
    if (g < N) DIS[g] = rsqrtf((float)myc + 1.0f);
    s[threadIdx.x] = myc;
    __syncthreads();
    for (int off = 1; off < 256; off <<= 1) {
        int t = (threadIdx.x >= off) ? s[threadIdx.x - off] : 0;
        __syncthreads();
        s[threadIdx.x] += t;
        __syncthreads();
    }
    if (g < N) rowptr[g + 1] = s[threadIdx.x];
    if (threadIdx.x == 255) partials[blockIdx.x] = s[255];
}
__global__ void k_scan2(int* __restrict__ partials, int nb) {
    __shared__ int s[256];
    int t = threadIdx.x;
    s[t] = (t < nb) ? partials[t] : 0;
    __syncthreads();
    for (int off = 1; off < 256; off <<= 1) {
        int v = (t >= off) ? s[t - off] : 0;
        __syncthreads();
        s[t] += v;
        __syncthreads();
    }
    partials[t] = (t == 0) ? 0 : s[t - 1];  // exclusive
}
__global__ void k_scan3b(int* __restrict__ rowptr, const int* __restrict__ partials,
                         int* __restrict__ cur, int N)
{
    int g = blockIdx.x * 256 + threadIdx.x;
    int add = partials[blockIdx.x];
    int oldprev = 0;
    if (g < N && threadIdx.x > 0) oldprev = rowptr[g];
    __syncthreads();
    if (g < N) {
        rowptr[g + 1] += add;
        cur[g] = (threadIdx.x == 0) ? add : oldprev + add;
        if (g == 0) rowptr[0] = 0;
    }
}
__global__ void k_fill(const int* __restrict__ src, const int* __restrict__ dst,
                       int* __restrict__ cur, int* __restrict__ colsrc, int E)
{
    int e = blockIdx.x * 256 + threadIdx.x;
    if (e < E) {
        int p = atomicAdd(&cur[dst[e]], 1);
        colsrc[p] = src[e];
    }
}

// --- Q (bf16, pre-scaled), K/V (bf16, per-lane [4K|4V]), SKIP=H@Wc+bc ------
__global__ __launch_bounds__(256) void k_h32_to_kvqs(
    const float* __restrict__ Hm,
    const float* __restrict__ Wq, const float* __restrict__ bq,
    const float* __restrict__ Wk, const float* __restrict__ bk,
    const float* __restrict__ Wv, const float* __restrict__ bv,
    const float* __restrict__ WCBl,
    unsigned short* __restrict__ Qb, unsigned short* __restrict__ KV,
    float* __restrict__ SKIP, int N)
{
    __shared__ float hs[8][33];
    int row0 = blockIdx.x * 8;
    int c = threadIdx.x;
    {
        int r = threadIdx.x >> 5, k = threadIdx.x & 31;
        int gr = row0 + r;
        hs[r][k] = (gr < N) ? Hm[(size_t)gr * D32 + k] : 0.f;
    }
    __syncthreads();
    float aQ[8], aK[8], aV[8], aS[8];
    float bQ = bq[c], bK = bk[c], bV = bv[c];
    float bS = (c < 32) ? WCBl[1024 + c] : 0.f;
#pragma unroll
    for (int r = 0; r < 8; ++r) { aQ[r] = bQ; aK[r] = bK; aV[r] = bV; aS[r] = bS; }
#pragma unroll 8
    for (int k = 0; k < 32; ++k) {
        float wq = Wq[k * HCH + c], wk = Wk[k * HCH + c], wv = Wv[k * HCH + c];
        float wc = (c < 32) ? WCBl[k * D32 + c] : 0.f;
#pragma unroll
        for (int r = 0; r < 8; ++r) {
            float h = hs[r][k];
            aQ[r] = fmaf(h, wq, aQ[r]);
            aK[r] = fmaf(h, wk, aK[r]);
            aV[r] = fmaf(h, wv, aV[r]);
            aS[r] = fmaf(h, wc, aS[r]);
        }
    }
    int hh = c >> 5, cc = c & 31, ss = cc >> 2, ii = cc & 3;
#pragma unroll
    for (int r = 0; r < 8; ++r) {
        int gr = row0 + r;
        if (gr < N) {
            Qb[(size_t)gr * HCH + c] = f2bf(aQ[r] * CSCALE);
            size_t kb = (size_t)gr * 512 + hh * 64 + ss * 8 + ii;
            KV[kb]     = f2bf(aK[r]);
            KV[kb + 4] = f2bf(aV[r]);
            if (c < 32) SKIP[(size_t)gr * D32 + c] = aS[r];
        }
    }
}

// --- fused attention: wave per dst node, group-of-8 prefetch ---------------
#define PROC(A, PIDX)                                                        \
    {                                                                        \
        float f0 = __uint_as_float(A.x << 16);                               \
        float f1 = __uint_as_float(A.x & 0xffff0000u);                       \
        float f2 = __uint_as_float(A.y << 16);                               \
        float f3 = __uint_as_float(A.y & 0xffff0000u);                       \
        float t = q0 * f0 + q1 * f1 + q2 * f2 + q3 * f3;                     \
        t += __shfl_xor(t, 1, 64);                                           \
        t += __shfl_xor(t, 2, 64);                                           \
        t += __shfl_xor(t, 4, 64);                                           \
        float wg = ((PIDX) <= pl) ? exp2f(t) : 0.f;                          \
        l += wg;                                                             \
        acc0 = fmaf(wg, __uint_as_float(A.z << 16), acc0);                   \
        acc1 = fmaf(wg, __uint_as_float(A.z & 0xffff0000u), acc1);           \
        acc2 = fmaf(wg, __uint_as_float(A.w << 16), acc2);                   \
        acc3 = fmaf(wg, __uint_as_float(A.w & 0xffff0000u), acc3);           \
    }
#define CLD(B, I) colsrc[(B) + (I) <= pl ? (B) + (I) : pl]

__global__ __launch_bounds__(256, 4) void k_attn(
    const uint4* __restrict__ KV4, const uint2* __restrict__ Qb2,
    const float* __restrict__ SKIP, float* __restrict__ H,
    const int* __restrict__ rowptr, const int* __restrict__ colsrc,
    const float* __restrict__ Wh,
    const float* __restrict__ Wg3, const float* __restrict__ DIS,
    unsigned short* __restrict__ XWout, int N)
{
    __shared__ float os[4][264];
    __shared__ float wgs[1024];
    bool fuse = (Wg3 != nullptr);
    if (fuse) {
        for (int i = threadIdx.x; i < 1024; i += 256) wgs[i] = Wg3[i];
    }
    int w = threadIdx.x >> 6, lane = threadIdx.x & 63;
    int d = blockIdx.x * 4 + w;
    bool act = d < N;

    float q0 = 0.f, q1 = 0.f, q2 = 0.f, q3 = 0.f;
    if (act) {
        uint2 qw = Qb2[(size_t)d * 64 + lane];
        q0 = __uint_as_float(qw.x << 16);
        q1 = __uint_as_float(qw.x & 0xffff0000u);
        q2 = __uint_as_float(qw.y << 16);
        q3 = __uint_as_float(qw.y & 0xffff0000u);
    }

    float l = 0.f, acc0 = 0.f, acc1 = 0.f, acc2 = 0.f, acc3 = 0.f;
    if (act) {
        int p0 = rowptr[d], p1 = rowptr[d + 1];
        if (p1 > p0) {
            int pl = p1 - 1;
            int s0 = CLD(p0, 0), s1 = CLD(p0, 1), s2 = CLD(p0, 2), s3 = CLD(p0, 3);
            int s4 = CLD(p0, 4), s5 = CLD(p0, 5), s6 = CLD(p0, 6), s7 = CLD(p0, 7);
            uint4 A0 = KV4[(size_t)s0 * 64 + lane];
            uint4 A1 = KV4[(size_t)s1 * 64 + lane];
            uint4 A2 = KV4[(size_t)s2 * 64 + lane];
            uint4 A3 = KV4[(size_t)s3 * 64 + lane];
            uint4 A4 = KV4[(size_t)s4 * 64 + lane];
            uint4 A5 = KV4[(size_t)s5 * 64 + lane];
            uint4 A6 = KV4[(size_t)s6 * 64 + lane];
            uint4 A7 = KV4[(size_t)s7 * 64 + lane];
#pragma unroll 1
            for (int base = p0; base < p1; base += 8) {
                int nb2 = base + 8;
                int t0 = CLD(nb2, 0), t1 = CLD(nb2, 1), t2 = CLD(nb2, 2), t3 = CLD(nb2, 3);
                int t4 = CLD(nb2, 4), t5 = CLD(nb2, 5), t6 = CLD(nb2, 6), t7 = CLD(nb2, 7);
                uint4 B0 = KV4[(size_t)t0 * 64 + lane];
                uint4 B1 = KV4[(size_t)t1 * 64 + lane];
                uint4 B2 = KV4[(size_t)t2 * 64 + lane];
                uint4 B3 = KV4[(size_t)t3 * 64 + lane];
                uint4 B4 = KV4[(size_t)t4 * 64 + lane];
                uint4 B5 = KV4[(size_t)t5 * 64 + lane];
                uint4 B6 = KV4[(size_t)t6 * 64 + lane];
                uint4 B7 = KV4[(size_t)t7 * 64 + lane];
                PROC(A0, base)
                PROC(A1, base + 1)
                PROC(A2, base + 2)
                PROC(A3, base + 3)
                PROC(A4, base + 4)
                PROC(A5, base + 5)
                PROC(A6, base + 6)
                PROC(A7, base + 7)
                A0 = B0; A1 = B1; A2 = B2; A3 = B3;
                A4 = B4; A5 = B5; A6 = B6; A7 = B7;
            }
        }
        float inv = (l > 0.f) ? 1.f / l : 0.f;
        int gch = (lane >> 3) * 32 + (lane & 7) * 4;
        os[w][gch + 0] = acc0 * inv;
        os[w][gch + 1] = acc1 * inv;
        os[w][gch + 2] = acc2 * inv;
        os[w][gch + 3] = acc3 * inv;
    }
    __syncthreads();

    if (act) {
        int c = lane & 31, half = lane >> 5;
        float a2 = half ? 0.f : SKIP[(size_t)d * D32 + c];
        int kb = half * 128;
#pragma unroll 8
        for (int kk = 0; kk < 128; ++kk)
            a2 = fmaf(os[w][kb + kk], Wh[(kb + kk) * D32 + c], a2);
        a2 += __shfl_xor(a2, 32, 64);
        if (lane < 32) {
            if (!fuse) {
                H[(size_t)d * D32 + c] = a2;
            } else {
                float dd = DIS[d];
                float s = 0.f;
#pragma unroll
                for (int k = 0; k < 32; ++k)
                    s = fmaf(__shfl(a2, k, 32), wgs[k * D32 + c], s);
                XWout[(size_t)d * D32 + c] = f2bf(dd * s);
            }
        }
    }
}

// --- GCN layer 3: gather bf16 XW rows; fused epilogue emits XW4 bf16 -------
__global__ __launch_bounds__(256) void k_gcn_f(
    const unsigned short* __restrict__ XWp, const float* __restrict__ DIS,
    const int* __restrict__ rowptr, const int* __restrict__ colsrc,
    const float* __restrict__ bg, const float* __restrict__ Wg4,
    unsigned short* __restrict__ XWout, int N)
{
    __shared__ float wgs[1024];
    for (int i = threadIdx.x; i < 1024; i += 256) wgs[i] = Wg4[i];
    __syncthreads();
    int g = threadIdx.x >> 5;
    int c = threadIdx.x & 31;
    int d = blockIdx.x * 8 + g;
    bool act = d < N;
    float acc = 0.f, dd = 0.f, h3 = 0.f;
    if (act) {
        acc = bfu(XWp[(size_t)d * D32 + c]);
        int p0 = rowptr[d], p1 = rowptr[d + 1];
        if (p1 > p0) {
            int pl = p1 - 1;
            unsigned short uA = XWp[(size_t)CLD(p0, 0) * D32 + c];
            unsigned short uB = XWp[(size_t)CLD(p0, 1) * D32 + c];
            unsigned short uC = XWp[(size_t)CLD(p0, 2) * D32 + c];
            unsigned short uD = XWp[(size_t)CLD(p0, 3) * D32 + c];
#pragma unroll 4
            for (int p = p0; p < p1; ++p) {
                unsigned short uN = XWp[(size_t)CLD(p, 4) * D32 + c];
                acc += bfu(uA);
                uA = uB; uB = uC; uC = uD; uD = uN;
            }
        }
        dd = DIS[d];
        h3 = dd * acc + bg[c];
    }
    // width-32 shuffle matmul (all lanes of the wave participate; inactive
    // nodes contribute zeros to their own group only)
    float s = 0.f;
#pragma unroll
    for (int k = 0; k < 32; ++k)
        s = fmaf(__shfl(h3, k, 32), wgs[k * D32 + c], s);
    if (act) XWout[(size_t)d * D32 + c] = f2bf(dd * s);
}

// --- GCN layer 4 (final): gather bf16, fp32 out ----------------------------
__global__ __launch_bounds__(256) void k_gcn_last(
    const unsigned short* __restrict__ XWp, const float* __restrict__ DIS,
    const int* __restrict__ rowptr, const int* __restrict__ colsrc,
    const float* __restrict__ bg, float* __restrict__ Out, int N)
{
    int g = threadIdx.x >> 5;
    int c = threadIdx.x & 31;
    int d = blockIdx.x * 8 + g;
    if (d >= N) return;
    float acc = bfu(XWp[(size_t)d * D32 + c]);
    int p0 = rowptr[d], p1 = rowptr[d + 1];
    if (p1 > p0) {
        int pl = p1 - 1;
        unsigned short uA = XWp[(size_t)CLD(p0, 0) * D32 + c];
        unsigned short uB = XWp[(size_t)CLD(p0, 1) * D32 + c];
        unsigned short uC = XWp[(size_t)CLD(p0, 2) * D32 + c];
        unsigned short uD = XWp[(size_t)CLD(p0, 3) * D32 + c];
#pragma unroll 4
        for (int p = p0; p < p1; ++p) {
            unsigned short uN = XWp[(size_t)CLD(p, 4) * D32 + c];
            acc += bfu(uA);
            uA = uB; uB = uC; uC = uD; uD = uN;
        }
    }
    Out[(size_t)d * D32 + c] = DIS[d] * acc + bg[c];
}

// ---------------------------------------------------------------------------
extern "C" void kernel_launch(void* const* d_in, const int* in_sizes, int n_in,
                              void* d_out, int out_size, void* d_ws, size_t ws_size,
                              hipStream_t stream)
{
    const float* x  = (const float*)d_in[0];
    const int*   ei = (const int*)d_in[1];
    const int N = in_sizes[0] / INCH;
    const int E = in_sizes[1] / 2;
    const int* src = ei;
    const int* dst = ei + E;

    const float* W_embed = (const float*)d_in[2];
    const float* b_embed = (const float*)d_in[3];
    const float* Wg3 = (const float*)d_in[24];
    const float* bg3 = (const float*)d_in[25];
    const float* Wg4 = (const float*)d_in[26];
    const float* bg4 = (const float*)d_in[27];

    unsigned short* KV  = (unsigned short*)d_ws;        // N*512 bf16
    unsigned short* Qb  = KV + (size_t)N * 512;         // N*256 bf16
    float* H      = (float*)(Qb + (size_t)N * HCH);     // N*32 f32
    float* SKIP   = H + (size_t)N * D32;                // N*32 f32
    unsigned short* XW1 = (unsigned short*)(SKIP + (size_t)N * D32);  // N*32 bf16
    unsigned short* XW2 = XW1 + (size_t)N * D32;        // N*32 bf16
    int*   rowptr = (int*)(XW2 + (size_t)N * D32);      // N+1
    int*   colsrc = rowptr + (N + 1);                   // E
    int*   cursor = colsrc + E;                         // N
    int*   partials = cursor + N;                       // 256
    float* DIS    = (float*)(partials + 256);           // N
    float* WCB    = DIS + N;                            // 2*1056
    float* out    = (float*)d_out;

    const int nb8 = (N + 7) / 8;
    const int nbN = (N + 255) / 256;
    const int nbE = (E + 255) / 256;

    hipMemsetAsync(cursor, 0, (size_t)N * sizeof(int), stream);

    k_embed<<<nb8 + 2 + nbE, 256, 0, stream>>>(
        x, W_embed, b_embed, H, N, nb8, E, dst, cursor,
        (const float*)d_in[10], (const float*)d_in[11],
        (const float*)d_in[12], (const float*)d_in[13],
        (const float*)d_in[20], (const float*)d_in[21],
        (const float*)d_in[22], (const float*)d_in[23], WCB);

    k_scan1<<<nbN, 256, 0, stream>>>(cursor, rowptr, partials, DIS, N);
    k_scan2<<<1, 256, 0, stream>>>(partials, nbN);
    k_scan3b<<<nbN, 256, 0, stream>>>(rowptr, partials, cursor, N);
    k_fill<<<nbE, 256, 0, stream>>>(src, dst, cursor, colsrc, E);

    for (int layer = 0; layer < 2; ++layer) {
        int base = 4 + layer * 10;
        const float* Wq = (const float*)d_in[base + 0];
        const float* bq = (const float*)d_in[base + 1];
        const float* Wk = (const float*)d_in[base + 2];
        const float* bk = (const float*)d_in[base + 3];
        const float* Wv = (const float*)d_in[base + 4];
        const float* bv = (const float*)d_in[base + 5];
        const float* Wh = (const float*)d_in[base + 8];

        k_h32_to_kvqs<<<nb8, 256, 0, stream>>>(
            H, Wq, bq, Wk, bk, Wv, bv, WCB + layer * 1056, Qb, KV, SKIP, N);
        k_attn<<<(N + 3) / 4, 256, 0, stream>>>(
            (const uint4*)KV, (const uint2*)Qb, SKIP, H, rowptr, colsrc, Wh,
            layer == 1 ? Wg3 : nullptr, DIS, XW1, N);
    }

    // GCN layer 3: gather XW1 -> fused Wg4 matmul -> XW2 (bf16)
    k_gcn_f<<<nb8, 256, 0, stream>>>(XW1, DIS, rowptr, colsrc, bg3, Wg4, XW2, N);
    // GCN layer 4: gather XW2 -> final output
    k_gcn_last<<<nb8, 256, 0, stream>>>(XW2, DIS, rowptr, colsrc, bg4, out, N);
}

// Round 8
// 450.582 us; speedup vs baseline: 1.0974x; 1.0974x over previous
//
#include <hip/hip_runtime.h>
#include <cstddef>

// ---------------------------------------------------------------------------
// GNN forward: embed+posenc -> 2x TransformerConv(8 heads x 32) -> 2x GCNConv
// N=50000, E=400000, IN=63, D=32, HC=256.
// R8: R6's attn loop (group-of-4 double-buffer, plain launch_bounds(256),
// occupancy ~79%) + R7's fusions (Q bf16, GCN GEMMs fused into producer
// epilogues, GCN rows bf16, edge-count fused into embed).
// No-max softmax; CSR built once; no per-edge atomics anywhere.
// ---------------------------------------------------------------------------

#define NH 8
#define HCH 256
#define D32 32
#define INCH 63
#define CSCALE 0.25503485356f   // log2(e) / sqrt(32)

__device__ __forceinline__ unsigned short f2bf(float f) {
    unsigned u = __float_as_uint(f);
    u += 0x7fff + ((u >> 16) & 1);   // RNE
    return (unsigned short)(u >> 16);
}
__device__ __forceinline__ float bfu(unsigned short u) {
    return __uint_as_float(((unsigned)u) << 16);
}

// inv_freq[j] = 10000^(-2j/32) = 10^(-j/4)
__device__ const float c_invf[16] = {
    1.0f, 0.5623413251903491f, 0.31622776601683794f, 0.17782794100389228f,
    0.1f, 0.05623413251903491f, 0.031622776601683791f, 0.017782794100389228f,
    0.01f, 0.005623413251903491f, 0.0031622776601683794f, 0.0017782794100389228f,
    0.001f, 0.0005623413251903491f, 0.00031622776601683794f, 0.00017782794100389227f
};

// --- embed (+ compose in 2 blocks, + edge-count in trailing blocks) --------
__global__ __launch_bounds__(256) void k_embed(
    const float* __restrict__ x, const float* __restrict__ W,
    const float* __restrict__ b, float* __restrict__ H, int N, int nbMain,
    int E, const int* __restrict__ dst, int* __restrict__ cnt,
    const float* __restrict__ Wsk1, const float* __restrict__ bsk1,
    const float* __restrict__ Wh1,  const float* __restrict__ bh1,
    const float* __restrict__ Wsk2, const float* __restrict__ bsk2,
    const float* __restrict__ Wh2,  const float* __restrict__ bh2,
    float* __restrict__ WCB)
{
    if (blockIdx.x >= nbMain + 2) {
        int e = (blockIdx.x - nbMain - 2) * 256 + threadIdx.x;
        if (e < E) atomicAdd(&cnt[dst[e]], 1);
        return;
    }
    if (blockIdx.x >= nbMain) {
        int lay = blockIdx.x - nbMain;
        const float* Wsk = lay ? Wsk2 : Wsk1;
        const float* bsk = lay ? bsk2 : bsk1;
        const float* Wh  = lay ? Wh2  : Wh1;
        const float* bh  = lay ? bh2  : bh1;
        float* o = WCB + lay * 1056;
        for (int i = threadIdx.x; i < D32 * D32 + D32; i += 256) {
            if (i < D32 * D32) {
                int r = i >> 5, c = i & 31;
                float a = 0.f;
                for (int k = 0; k < HCH; ++k) a = fmaf(Wsk[r * HCH + k], Wh[k * D32 + c], a);
                o[i] = a;
            } else {
                int c = i - D32 * D32;
                float a = bh[c];
                for (int k = 0; k < HCH; ++k) a = fmaf(bsk[k], Wh[k * D32 + c], a);
                o[1024 + c] = a;
            }
        }
        return;
    }
    __shared__ float xs[8][64];
    __shared__ float ws[INCH * D32];
    int row0 = blockIdx.x * 8;
    for (int i = threadIdx.x; i < INCH * D32; i += 256) ws[i] = W[i];
    for (int i = threadIdx.x; i < 8 * INCH; i += 256) {
        int r = i / INCH, cc = i % INCH;
        int gr = row0 + r;
        xs[r][cc] = (gr < N) ? x[(size_t)gr * INCH + cc] : 0.f;
    }
    __syncthreads();
    int lr = threadIdx.x >> 5, c = threadIdx.x & 31;
    int row = row0 + lr;
    if (row >= N) return;
    float acc = b[c];
#pragma unroll
    for (int k = 0; k < INCH; ++k) acc = fmaf(xs[lr][k], ws[k * D32 + c], acc);
    float phase = (float)row * c_invf[c >> 1];
    float pe = (c & 1) ? cosf(phase) : sinf(phase);
    H[(size_t)row * D32 + c] = acc + pe;
}

// --- CSR build -------------------------------------------------------------
__global__ void k_scan1(const int* __restrict__ cnt, int* __restrict__ rowptr,
                        int* __restrict__ partials, float* __restrict__ DIS, int N)
{
    __shared__ int s[256];
    int g = blockIdx.x * 256 + threadIdx.x;
    int myc = (g < N) ? cnt[g] : 0;
    if (g < N) DIS[g] = rsqrtf((float)myc + 1.0f);
    s[threadIdx.x] = myc;
    __syncthreads();
    for (int off = 1; off < 256; off <<= 1) {
        int t = (threadIdx.x >= off) ? s[threadIdx.x - off] : 0;
        __syncthreads();
        s[threadIdx.x] += t;
        __syncthreads();
    }
    if (g < N) rowptr[g + 1] = s[threadIdx.x];
    if (threadIdx.x == 255) partials[blockIdx.x] = s[255];
}
__global__ void k_scan2(int* __restrict__ partials, int nb) {
    __shared__ int s[256];
    int t = threadIdx.x;
    s[t] = (t < nb) ? partials[t] : 0;
    __syncthreads();
    for (int off = 1; off < 256; off <<= 1) {
        int v = (t >= off) ? s[t - off] : 0;
        __syncthreads();
        s[t] += v;
        __syncthreads();
    }
    partials[t] = (t == 0) ? 0 : s[t - 1];  // exclusive
}
__global__ void k_scan3b(int* __restrict__ rowptr, const int* __restrict__ partials,
                         int* __restrict__ cur, int N)
{
    int g = blockIdx.x * 256 + threadIdx.x;
    int add = partials[blockIdx.x];
    int oldprev = 0;
    if (g < N && threadIdx.x > 0) oldprev = rowptr[g];
    __syncthreads();
    if (g < N) {
        rowptr[g + 1] += add;
        cur[g] = (threadIdx.x == 0) ? add : oldprev + add;
        if (g == 0) rowptr[0] = 0;
    }
}
__global__ void k_fill(const int* __restrict__ src, const int* __restrict__ dst,
                       int* __restrict__ cur, int* __restrict__ colsrc, int E)
{
    int e = blockIdx.x * 256 + threadIdx.x;
    if (e < E) {
        int p = atomicAdd(&cur[dst[e]], 1);
        colsrc[p] = src[e];
    }
}

// --- Q (bf16, pre-scaled), K/V (bf16, per-lane [4K|4V]), SKIP=H@Wc+bc ------
__global__ __launch_bounds__(256) void k_h32_to_kvqs(
    const float* __restrict__ Hm,
    const float* __restrict__ Wq, const float* __restrict__ bq,
    const float* __restrict__ Wk, const float* __restrict__ bk,
    const float* __restrict__ Wv, const float* __restrict__ bv,
    const float* __restrict__ WCBl,
    unsigned short* __restrict__ Qb, unsigned short* __restrict__ KV,
    float* __restrict__ SKIP, int N)
{
    __shared__ float hs[8][33];
    int row0 = blockIdx.x * 8;
    int c = threadIdx.x;
    {
        int r = threadIdx.x >> 5, k = threadIdx.x & 31;
        int gr = row0 + r;
        hs[r][k] = (gr < N) ? Hm[(size_t)gr * D32 + k] : 0.f;
    }
    __syncthreads();
    float aQ[8], aK[8], aV[8], aS[8];
    float bQ = bq[c], bK = bk[c], bV = bv[c];
    float bS = (c < 32) ? WCBl[1024 + c] : 0.f;
#pragma unroll
    for (int r = 0; r < 8; ++r) { aQ[r] = bQ; aK[r] = bK; aV[r] = bV; aS[r] = bS; }
#pragma unroll 8
    for (int k = 0; k < 32; ++k) {
        float wq = Wq[k * HCH + c], wk = Wk[k * HCH + c], wv = Wv[k * HCH + c];
        float wc = (c < 32) ? WCBl[k * D32 + c] : 0.f;
#pragma unroll
        for (int r = 0; r < 8; ++r) {
            float h = hs[r][k];
            aQ[r] = fmaf(h, wq, aQ[r]);
            aK[r] = fmaf(h, wk, aK[r]);
            aV[r] = fmaf(h, wv, aV[r]);
            aS[r] = fmaf(h, wc, aS[r]);
        }
    }
    int hh = c >> 5, cc = c & 31, ss = cc >> 2, ii = cc & 3;
#pragma unroll
    for (int r = 0; r < 8; ++r) {
        int gr = row0 + r;
        if (gr < N) {
            Qb[(size_t)gr * HCH + c] = f2bf(aQ[r] * CSCALE);
            size_t kb = (size_t)gr * 512 + hh * 64 + ss * 8 + ii;
            KV[kb]     = f2bf(aK[r]);
            KV[kb + 4] = f2bf(aV[r]);
            if (c < 32) SKIP[(size_t)gr * D32 + c] = aS[r];
        }
    }
}

// --- fused attention: wave per dst node, group-of-4 double-buffered --------
#define PROC(A, PIDX)                                                        \
    {                                                                        \
        float f0 = __uint_as_float(A.x << 16);                               \
        float f1 = __uint_as_float(A.x & 0xffff0000u);                       \
        float f2 = __uint_as_float(A.y << 16);                               \
        float f3 = __uint_as_float(A.y & 0xffff0000u);                       \
        float t = q0 * f0 + q1 * f1 + q2 * f2 + q3 * f3;                     \
        t += __shfl_xor(t, 1, 64);                                           \
        t += __shfl_xor(t, 2, 64);                                           \
        t += __shfl_xor(t, 4, 64);                                           \
        float wg = ((PIDX) <= pl) ? exp2f(t) : 0.f;                          \
        l += wg;                                                             \
        acc0 = fmaf(wg, __uint_as_float(A.z << 16), acc0);                   \
        acc1 = fmaf(wg, __uint_as_float(A.z & 0xffff0000u), acc1);           \
        acc2 = fmaf(wg, __uint_as_float(A.w << 16), acc2);                   \
        acc3 = fmaf(wg, __uint_as_float(A.w & 0xffff0000u), acc3);           \
    }
#define CLD(B, I) colsrc[(B) + (I) <= pl ? (B) + (I) : pl]

__global__ __launch_bounds__(256) void k_attn(
    const uint4* __restrict__ KV4, const uint2* __restrict__ Qb2,
    const float* __restrict__ SKIP, float* __restrict__ H,
    const int* __restrict__ rowptr, const int* __restrict__ colsrc,
    const float* __restrict__ Wh,
    const float* __restrict__ Wg3, const float* __restrict__ DIS,
    unsigned short* __restrict__ XWout, int N)
{
    __shared__ float os[4][264];
    __shared__ float wgs[1024];
    bool fuse = (Wg3 != nullptr);
    if (fuse) {
        for (int i = threadIdx.x; i < 1024; i += 256) wgs[i] = Wg3[i];
    }
    int w = threadIdx.x >> 6, lane = threadIdx.x & 63;
    int d = blockIdx.x * 4 + w;
    bool act = d < N;

    float q0 = 0.f, q1 = 0.f, q2 = 0.f, q3 = 0.f;
    if (act) {
        uint2 qw = Qb2[(size_t)d * 64 + lane];
        q0 = __uint_as_float(qw.x << 16);
        q1 = __uint_as_float(qw.x & 0xffff0000u);
        q2 = __uint_as_float(qw.y << 16);
        q3 = __uint_as_float(qw.y & 0xffff0000u);
    }

    float l = 0.f, acc0 = 0.f, acc1 = 0.f, acc2 = 0.f, acc3 = 0.f;
    if (act) {
        int p0 = rowptr[d], p1 = rowptr[d + 1];
        if (p1 > p0) {
            int pl = p1 - 1;
            int s0 = CLD(p0, 0), s1 = CLD(p0, 1), s2 = CLD(p0, 2), s3 = CLD(p0, 3);
            uint4 A0 = KV4[(size_t)s0 * 64 + lane];
            uint4 A1 = KV4[(size_t)s1 * 64 + lane];
            uint4 A2 = KV4[(size_t)s2 * 64 + lane];
            uint4 A3 = KV4[(size_t)s3 * 64 + lane];
#pragma unroll 2
            for (int base = p0; base < p1; base += 4) {
                int nb2 = base + 4;
                int t0 = CLD(nb2, 0), t1 = CLD(nb2, 1), t2 = CLD(nb2, 2), t3 = CLD(nb2, 3);
                uint4 B0 = KV4[(size_t)t0 * 64 + lane];
                uint4 B1 = KV4[(size_t)t1 * 64 + lane];
                uint4 B2 = KV4[(size_t)t2 * 64 + lane];
                uint4 B3 = KV4[(size_t)t3 * 64 + lane];
                PROC(A0, base)
                PROC(A1, base + 1)
                PROC(A2, base + 2)
                PROC(A3, base + 3)
                A0 = B0; A1 = B1; A2 = B2; A3 = B3;
            }
        }
        float inv = (l > 0.f) ? 1.f / l : 0.f;
        int gch = (lane >> 3) * 32 + (lane & 7) * 4;
        os[w][gch + 0] = acc0 * inv;
        os[w][gch + 1] = acc1 * inv;
        os[w][gch + 2] = acc2 * inv;
        os[w][gch + 3] = acc3 * inv;
    }
    __syncthreads();

    if (act) {
        int c = lane & 31, half = lane >> 5;
        float a2 = half ? 0.f : SKIP[(size_t)d * D32 + c];
        int kb = half * 128;
#pragma unroll 8
        for (int kk = 0; kk < 128; ++kk)
            a2 = fmaf(os[w][kb + kk], Wh[(kb + kk) * D32 + c], a2);
        a2 += __shfl_xor(a2, 32, 64);
        if (lane < 32) {
            if (!fuse) {
                H[(size_t)d * D32 + c] = a2;
            } else {
                float dd = DIS[d];
                float s = 0.f;
#pragma unroll
                for (int k = 0; k < 32; ++k)
                    s = fmaf(__shfl(a2, k, 32), wgs[k * D32 + c], s);
                XWout[(size_t)d * D32 + c] = f2bf(dd * s);
            }
        }
    }
}

// --- GCN layer 3: gather bf16 XW rows; fused epilogue emits XW4 bf16 -------
__global__ __launch_bounds__(256) void k_gcn_f(
    const unsigned short* __restrict__ XWp, const float* __restrict__ DIS,
    const int* __restrict__ rowptr, const int* __restrict__ colsrc,
    const float* __restrict__ bg, const float* __restrict__ Wg4,
    unsigned short* __restrict__ XWout, int N)
{
    __shared__ float wgs[1024];
    for (int i = threadIdx.x; i < 1024; i += 256) wgs[i] = Wg4[i];
    __syncthreads();
    int g = threadIdx.x >> 5;
    int c = threadIdx.x & 31;
    int d = blockIdx.x * 8 + g;
    bool act = d < N;
    float acc = 0.f, dd = 0.f, h3 = 0.f;
    if (act) {
        acc = bfu(XWp[(size_t)d * D32 + c]);
        int p0 = rowptr[d], p1 = rowptr[d + 1];
        if (p1 > p0) {
            int pl = p1 - 1;
            unsigned short uA = XWp[(size_t)CLD(p0, 0) * D32 + c];
            unsigned short uB = XWp[(size_t)CLD(p0, 1) * D32 + c];
            unsigned short uC = XWp[(size_t)CLD(p0, 2) * D32 + c];
            unsigned short uD = XWp[(size_t)CLD(p0, 3) * D32 + c];
#pragma unroll 4
            for (int p = p0; p < p1; ++p) {
                unsigned short uN = XWp[(size_t)CLD(p, 4) * D32 + c];
                acc += bfu(uA);
                uA = uB; uB = uC; uC = uD; uD = uN;
            }
        }
        dd = DIS[d];
        h3 = dd * acc + bg[c];
    }
    float s = 0.f;
#pragma unroll
    for (int k = 0; k < 32; ++k)
        s = fmaf(__shfl(h3, k, 32), wgs[k * D32 + c], s);
    if (act) XWout[(size_t)d * D32 + c] = f2bf(dd * s);
}

// --- GCN layer 4 (final): gather bf16, fp32 out ----------------------------
__global__ __launch_bounds__(256) void k_gcn_last(
    const unsigned short* __restrict__ XWp, const float* __restrict__ DIS,
    const int* __restrict__ rowptr, const int* __restrict__ colsrc,
    const float* __restrict__ bg, float* __restrict__ Out, int N)
{
    int g = threadIdx.x >> 5;
    int c = threadIdx.x & 31;
    int d = blockIdx.x * 8 + g;
    if (d >= N) return;
    float acc = bfu(XWp[(size_t)d * D32 + c]);
    int p0 = rowptr[d], p1 = rowptr[d + 1];
    if (p1 > p0) {
        int pl = p1 - 1;
        unsigned short uA = XWp[(size_t)CLD(p0, 0) * D32 + c];
        unsigned short uB = XWp[(size_t)CLD(p0, 1) * D32 + c];
        unsigned short uC = XWp[(size_t)CLD(p0, 2) * D32 + c];
        unsigned short uD = XWp[(size_t)CLD(p0, 3) * D32 + c];
#pragma unroll 4
        for (int p = p0; p < p1; ++p) {
            unsigned short uN = XWp[(size_t)CLD(p, 4) * D32 + c];
            acc += bfu(uA);
            uA = uB; uB = uC; uC = uD; uD = uN;
        }
    }
    Out[(size_t)d * D32 + c] = DIS[d] * acc + bg[c];
}

// ---------------------------------------------------------------------------
extern "C" void kernel_launch(void* const* d_in, const int* in_sizes, int n_in,
                              void* d_out, int out_size, void* d_ws, size_t ws_size,
                              hipStream_t stream)
{
    const float* x  = (const float*)d_in[0];
    const int*   ei = (const int*)d_in[1];
    const int N = in_sizes[0] / INCH;
    const int E = in_sizes[1] / 2;
    const int* src = ei;
    const int* dst = ei + E;

    const float* W_embed = (const float*)d_in[2];
    const float* b_embed = (const float*)d_in[3];
    const float* Wg3 = (const float*)d_in[24];
    const float* bg3 = (const float*)d_in[25];
    const float* Wg4 = (const float*)d_in[26];
    const float* bg4 = (const float*)d_in[27];

    unsigned short* KV  = (unsigned short*)d_ws;        // N*512 bf16
    unsigned short* Qb  = KV + (size_t)N * 512;         // N*256 bf16
    float* H      = (float*)(Qb + (size_t)N * HCH);     // N*32 f32
    float* SKIP   = H + (size_t)N * D32;                // N*32 f32
    unsigned short* XW1 = (unsigned short*)(SKIP + (size_t)N * D32);  // N*32 bf16
    unsigned short* XW2 = XW1 + (size_t)N * D32;        // N*32 bf16
    int*   rowptr = (int*)(XW2 + (size_t)N * D32);      // N+1
    int*   colsrc = rowptr + (N + 1);                   // E
    int*   cursor = colsrc + E;                         // N
    int*   partials = cursor + N;                       // 256
    float* DIS    = (float*)(partials + 256);           // N
    float* WCB    = DIS + N;                            // 2*1056
    float* out    = (float*)d_out;

    const int nb8 = (N + 7) / 8;
    const int nbN = (N + 255) / 256;
    const int nbE = (E + 255) / 256;

    hipMemsetAsync(cursor, 0, (size_t)N * sizeof(int), stream);

    k_embed<<<nb8 + 2 + nbE, 256, 0, stream>>>(
        x, W_embed, b_embed, H, N, nb8, E, dst, cursor,
        (const float*)d_in[10], (const float*)d_in[11],
        (const float*)d_in[12], (const float*)d_in[13],
        (const float*)d_in[20], (const float*)d_in[21],
        (const float*)d_in[22], (const float*)d_in[23], WCB);

    k_scan1<<<nbN, 256, 0, stream>>>(cursor, rowptr, partials, DIS, N);
    k_scan2<<<1, 256, 0, stream>>>(partials, nbN);
    k_scan3b<<<nbN, 256, 0, stream>>>(rowptr, partials, cursor, N);
    k_fill<<<nbE, 256, 0, stream>>>(src, dst, cursor, colsrc, E);

    for (int layer = 0; layer < 2; ++layer) {
        int base = 4 + layer * 10;
        const float* Wq = (const float*)d_in[base + 0];
        const float* bq = (const float*)d_in[base + 1];
        const float* Wk = (const float*)d_in[base + 2];
        const float* bk = (const float*)d_in[base + 3];
        const float* Wv = (const float*)d_in[base + 4];
        const float* bv = (const float*)d_in[base + 5];
        const float* Wh = (const float*)d_in[base + 8];

        k_h32_to_kvqs<<<nb8, 256, 0, stream>>>(
            H, Wq, bq, Wk, bk, Wv, bv, WCB + layer * 1056, Qb, KV, SKIP, N);
        k_attn<<<(N + 3) / 4, 256, 0, stream>>>(
            (const uint4*)KV, (const uint2*)Qb, SKIP, H, rowptr, colsrc, Wh,
            layer == 1 ? Wg3 : nullptr, DIS, XW1, N);
    }

    // GCN layer 3: gather XW1 -> fused Wg4 matmul -> XW2 (bf16)
    k_gcn_f<<<nb8, 256, 0, stream>>>(XW1, DIS, rowptr, colsrc, bg3, Wg4, XW2, N);
    // GCN layer 4: gather XW2 -> final output
    k_gcn_last<<<nb8, 256, 0, stream>>>(XW2, DIS, rowptr, colsrc, bg4, out, N);
}

// Round 9
// 434.313 us; speedup vs baseline: 1.1385x; 1.0375x over previous
//
#include <hip/hip_runtime.h>
#include <cstddef>

// ---------------------------------------------------------------------------
// GNN forward: embed+posenc -> 2x TransformerConv(8 heads x 32) -> 2x GCNConv
// N=50000, E=400000, IN=63, D=32, HC=256.
// R9: k_attn restored to the R6-proven shape (group-of-4 double-buffer, plain
// launch_bounds, small LDS, fp32 H write, no fuse) + Q read as bf16.
// XW3 GEMM is its own cheap pass; Wg4 stays fused in k_gcn_f.
// No-max softmax; CSR built once; no per-edge atomics anywhere.
// ---------------------------------------------------------------------------

#define NH 8
#define HCH 256
#define D32 32
#define INCH 63
#define CSCALE 0.25503485356f   // log2(e) / sqrt(32)

__device__ __forceinline__ unsigned short f2bf(float f) {
    unsigned u = __float_as_uint(f);
    u += 0x7fff + ((u >> 16) & 1);   // RNE
    return (unsigned short)(u >> 16);
}
__device__ __forceinline__ float bfu(unsigned short u) {
    return __uint_as_float(((unsigned)u) << 16);
}

// inv_freq[j] = 10000^(-2j/32) = 10^(-j/4)
__device__ const float c_invf[16] = {
    1.0f, 0.5623413251903491f, 0.31622776601683794f, 0.17782794100389228f,
    0.1f, 0.05623413251903491f, 0.031622776601683791f, 0.017782794100389228f,
    0.01f, 0.005623413251903491f, 0.0031622776601683794f, 0.0017782794100389228f,
    0.001f, 0.0005623413251903491f, 0.00031622776601683794f, 0.00017782794100389227f
};

// --- embed (+ compose in 2 blocks, + edge-count in trailing blocks) --------
__global__ __launch_bounds__(256) void k_embed(
    const float* __restrict__ x, const float* __restrict__ W,
    const float* __restrict__ b, float* __restrict__ H, int N, int nbMain,
    int E, const int* __restrict__ dst, int* __restrict__ cnt,
    const float* __restrict__ Wsk1, const float* __restrict__ bsk1,
    const float* __restrict__ Wh1,  const float* __restrict__ bh1,
    const float* __restrict__ Wsk2, const float* __restrict__ bsk2,
    const float* __restrict__ Wh2,  const float* __restrict__ bh2,
    float* __restrict__ WCB)
{
    if (blockIdx.x >= nbMain + 2) {
        int e = (blockIdx.x - nbMain - 2) * 256 + threadIdx.x;
        if (e < E) atomicAdd(&cnt[dst[e]], 1);
        return;
    }
    if (blockIdx.x >= nbMain) {
        int lay = blockIdx.x - nbMain;
        const float* Wsk = lay ? Wsk2 : Wsk1;
        const float* bsk = lay ? bsk2 : bsk1;
        const float* Wh  = lay ? Wh2  : Wh1;
        const float* bh  = lay ? bh2  : bh1;
        float* o = WCB + lay * 1056;
        for (int i = threadIdx.x; i < D32 * D32 + D32; i += 256) {
            if (i < D32 * D32) {
                int r = i >> 5, c = i & 31;
                float a = 0.f;
                for (int k = 0; k < HCH; ++k) a = fmaf(Wsk[r * HCH + k], Wh[k * D32 + c], a);
                o[i] = a;
            } else {
                int c = i - D32 * D32;
                float a = bh[c];
                for (int k = 0; k < HCH; ++k) a = fmaf(bsk[k], Wh[k * D32 + c], a);
                o[1024 + c] = a;
            }
        }
        return;
    }
    __shared__ float xs[8][64];
    __shared__ float ws[INCH * D32];
    int row0 = blockIdx.x * 8;
    for (int i = threadIdx.x; i < INCH * D32; i += 256) ws[i] = W[i];
    for (int i = threadIdx.x; i < 8 * INCH; i += 256) {
        int r = i / INCH, cc = i % INCH;
        int gr = row0 + r;
        xs[r][cc] = (gr < N) ? x[(size_t)gr * INCH + cc] : 0.f;
    }
    __syncthreads();
    int lr = threadIdx.x >> 5, c = threadIdx.x & 31;
    int row = row0 + lr;
    if (row >= N) return;
    float acc = b[c];
#pragma unroll
    for (int k = 0; k < INCH; ++k) acc = fmaf(xs[lr][k], ws[k * D32 + c], acc);
    float phase = (float)row * c_invf[c >> 1];
    float pe = (c & 1) ? cosf(phase) : sinf(phase);
    H[(size_t)row * D32 + c] = acc + pe;
}

// --- CSR build -------------------------------------------------------------
__global__ void k_scan1(const int* __restrict__ cnt, int* __restrict__ rowptr,
                        int* __restrict__ partials, float* __restrict__ DIS, int N)
{
    __shared__ int s[256];
    int g = blockIdx.x * 256 + threadIdx.x;
    int myc = (g < N) ? cnt[g] : 0;
    if (g < N) DIS[g] = rsqrtf((float)myc + 1.0f);
    s[threadIdx.x] = myc;
    __syncthreads();
    for (int off = 1; off < 256; off <<= 1) {
        int t = (threadIdx.x >= off) ? s[threadIdx.x - off] : 0;
        __syncthreads();
        s[threadIdx.x] += t;
        __syncthreads();
    }
    if (g < N) rowptr[g + 1] = s[threadIdx.x];
    if (threadIdx.x == 255) partials[blockIdx.x] = s[255];
}
__global__ void k_scan2(int* __restrict__ partials, int nb) {
    __shared__ int s[256];
    int t = threadIdx.x;
    s[t] = (t < nb) ? partials[t] : 0;
    __syncthreads();
    for (int off = 1; off < 256; off <<= 1) {
        int v = (t >= off) ? s[t - off] : 0;
        __syncthreads();
        s[t] += v;
        __syncthreads();
    }
    partials[t] = (t == 0) ? 0 : s[t - 1];  // exclusive
}
__global__ void k_scan3b(int* __restrict__ rowptr, const int* __restrict__ partials,
                         int* __restrict__ cur, int N)
{
    int g = blockIdx.x * 256 + threadIdx.x;
    int add = partials[blockIdx.x];
    int oldprev = 0;
    if (g < N && threadIdx.x > 0) oldprev = rowptr[g];
    __syncthreads();
    if (g < N) {
        rowptr[g + 1] += add;
        cur[g] = (threadIdx.x == 0) ? add : oldprev + add;
        if (g == 0) rowptr[0] = 0;
    }
}
__global__ void k_fill(const int* __restrict__ src, const int* __restrict__ dst,
                       int* __restrict__ cur, int* __restrict__ colsrc, int E)
{
    int e = blockIdx.x * 256 + threadIdx.x;
    if (e < E) {
        int p = atomicAdd(&cur[dst[e]], 1);
        colsrc[p] = src[e];
    }
}

// --- Q (bf16, pre-scaled), K/V (bf16, per-lane [4K|4V]), SKIP=H@Wc+bc ------
__global__ __launch_bounds__(256) void k_h32_to_kvqs(
    const float* __restrict__ Hm,
    const float* __restrict__ Wq, const float* __restrict__ bq,
    const float* __restrict__ Wk, const float* __restrict__ bk,
    const float* __restrict__ Wv, const float* __restrict__ bv,
    const float* __restrict__ WCBl,
    unsigned short* __restrict__ Qb, unsigned short* __restrict__ KV,
    float* __restrict__ SKIP, int N)
{
    __shared__ float hs[8][33];
    int row0 = blockIdx.x * 8;
    int c = threadIdx.x;
    {
        int r = threadIdx.x >> 5, k = threadIdx.x & 31;
        int gr = row0 + r;
        hs[r][k] = (gr < N) ? Hm[(size_t)gr * D32 + k] : 0.f;
    }
    __syncthreads();
    float aQ[8], aK[8], aV[8], aS[8];
    float bQ = bq[c], bK = bk[c], bV = bv[c];
    float bS = (c < 32) ? WCBl[1024 + c] : 0.f;
#pragma unroll
    for (int r = 0; r < 8; ++r) { aQ[r] = bQ; aK[r] = bK; aV[r] = bV; aS[r] = bS; }
#pragma unroll 8
    for (int k = 0; k < 32; ++k) {
        float wq = Wq[k * HCH + c], wk = Wk[k * HCH + c], wv = Wv[k * HCH + c];
        float wc = (c < 32) ? WCBl[k * D32 + c] : 0.f;
#pragma unroll
        for (int r = 0; r < 8; ++r) {
            float h = hs[r][k];
            aQ[r] = fmaf(h, wq, aQ[r]);
            aK[r] = fmaf(h, wk, aK[r]);
            aV[r] = fmaf(h, wv, aV[r]);
            aS[r] = fmaf(h, wc, aS[r]);
        }
    }
    int hh = c >> 5, cc = c & 31, ss = cc >> 2, ii = cc & 3;
#pragma unroll
    for (int r = 0; r < 8; ++r) {
        int gr = row0 + r;
        if (gr < N) {
            Qb[(size_t)gr * HCH + c] = f2bf(aQ[r] * CSCALE);
            size_t kb = (size_t)gr * 512 + hh * 64 + ss * 8 + ii;
            KV[kb]     = f2bf(aK[r]);
            KV[kb + 4] = f2bf(aV[r]);
            if (c < 32) SKIP[(size_t)gr * D32 + c] = aS[r];
        }
    }
}

// --- fused attention: wave per dst node, group-of-4 double-buffered --------
#define PROC(A, PIDX)                                                        \
    {                                                                        \
        float f0 = __uint_as_float(A.x << 16);                               \
        float f1 = __uint_as_float(A.x & 0xffff0000u);                       \
        float f2 = __uint_as_float(A.y << 16);                               \
        float f3 = __uint_as_float(A.y & 0xffff0000u);                       \
        float t = q0 * f0 + q1 * f1 + q2 * f2 + q3 * f3;                     \
        t += __shfl_xor(t, 1, 64);                                           \
        t += __shfl_xor(t, 2, 64);                                           \
        t += __shfl_xor(t, 4, 64);                                           \
        float wg = ((PIDX) <= pl) ? exp2f(t) : 0.f;                          \
        l += wg;                                                             \
        acc0 = fmaf(wg, __uint_as_float(A.z << 16), acc0);                   \
        acc1 = fmaf(wg, __uint_as_float(A.z & 0xffff0000u), acc1);           \
        acc2 = fmaf(wg, __uint_as_float(A.w << 16), acc2);                   \
        acc3 = fmaf(wg, __uint_as_float(A.w & 0xffff0000u), acc3);           \
    }
#define CLD(B, I) colsrc[min((B) + (I), pl)]

__global__ __launch_bounds__(256) void k_attn(
    const uint4* __restrict__ KV4, const uint2* __restrict__ Qb2,
    const float* __restrict__ SKIP, float* __restrict__ H,
    const int* __restrict__ rowptr, const int* __restrict__ colsrc,
    const float* __restrict__ Wh, int N)
{
    __shared__ float os[4][264];
    int w = threadIdx.x >> 6, lane = threadIdx.x & 63;
    int d = blockIdx.x * 4 + w;
    bool act = d < N;

    float q0 = 0.f, q1 = 0.f, q2 = 0.f, q3 = 0.f;
    if (act) {
        uint2 qw = Qb2[(size_t)d * 64 + lane];
        q0 = __uint_as_float(qw.x << 16);
        q1 = __uint_as_float(qw.x & 0xffff0000u);
        q2 = __uint_as_float(qw.y << 16);
        q3 = __uint_as_float(qw.y & 0xffff0000u);
    }

    float l = 0.f, acc0 = 0.f, acc1 = 0.f, acc2 = 0.f, acc3 = 0.f;
    if (act) {
        int p0 = rowptr[d], p1 = rowptr[d + 1];
        if (p1 > p0) {
            int pl = p1 - 1;
            int s0 = CLD(p0, 0), s1 = CLD(p0, 1), s2 = CLD(p0, 2), s3 = CLD(p0, 3);
            uint4 A0 = KV4[(size_t)s0 * 64 + lane];
            uint4 A1 = KV4[(size_t)s1 * 64 + lane];
            uint4 A2 = KV4[(size_t)s2 * 64 + lane];
            uint4 A3 = KV4[(size_t)s3 * 64 + lane];
#pragma unroll 2
            for (int base = p0; base < p1; base += 4) {
                int nb2 = base + 4;
                int t0 = CLD(nb2, 0), t1 = CLD(nb2, 1), t2 = CLD(nb2, 2), t3 = CLD(nb2, 3);
                uint4 B0 = KV4[(size_t)t0 * 64 + lane];
                uint4 B1 = KV4[(size_t)t1 * 64 + lane];
                uint4 B2 = KV4[(size_t)t2 * 64 + lane];
                uint4 B3 = KV4[(size_t)t3 * 64 + lane];
                PROC(A0, base)
                PROC(A1, base + 1)
                PROC(A2, base + 2)
                PROC(A3, base + 3)
                A0 = B0; A1 = B1; A2 = B2; A3 = B3;
            }
        }
        float inv = (l > 0.f) ? 1.f / l : 0.f;
        int gch = (lane >> 3) * 32 + (lane & 7) * 4;
        os[w][gch + 0] = acc0 * inv;
        os[w][gch + 1] = acc1 * inv;
        os[w][gch + 2] = acc2 * inv;
        os[w][gch + 3] = acc3 * inv;
    }
    __syncthreads();

    if (act) {
        int c = lane & 31, half = lane >> 5;
        float a2 = half ? 0.f : SKIP[(size_t)d * D32 + c];
        int kb = half * 128;
#pragma unroll 8
        for (int kk = 0; kk < 128; ++kk)
            a2 = fmaf(os[w][kb + kk], Wh[(kb + kk) * D32 + c], a2);
        a2 += __shfl_xor(a2, 32, 64);
        if (lane < 32) H[(size_t)d * D32 + c] = a2;
    }
}

// --- XW3 = DIS * (H @ Wg3), bf16 out ---------------------------------------
__global__ __launch_bounds__(256) void k_xw3(
    const float* __restrict__ X, const float* __restrict__ W,
    const float* __restrict__ DIS, unsigned short* __restrict__ O, int N)
{
    __shared__ float xs[8][33];
    __shared__ float ws[D32 * D32];
    int row0 = blockIdx.x * 8;
    int c = threadIdx.x & 31, lr = threadIdx.x >> 5;
    for (int i = threadIdx.x; i < D32 * D32; i += 256) ws[i] = W[i];
    {
        int gr = row0 + lr;
        xs[lr][c] = (gr < N) ? X[(size_t)gr * D32 + c] : 0.f;
    }
    __syncthreads();
    int row = row0 + lr;
    if (row >= N) return;
    float acc = 0.f;
#pragma unroll
    for (int k = 0; k < D32; ++k) acc = fmaf(xs[lr][k], ws[k * D32 + c], acc);
    O[(size_t)row * D32 + c] = f2bf(DIS[row] * acc);
}

// --- GCN layer 3: gather bf16 XW rows; fused epilogue emits XW4 bf16 -------
__global__ __launch_bounds__(256) void k_gcn_f(
    const unsigned short* __restrict__ XWp, const float* __restrict__ DIS,
    const int* __restrict__ rowptr, const int* __restrict__ colsrc,
    const float* __restrict__ bg, const float* __restrict__ Wg4,
    unsigned short* __restrict__ XWout, int N)
{
    __shared__ float wgs[1024];
    for (int i = threadIdx.x; i < 1024; i += 256) wgs[i] = Wg4[i];
    __syncthreads();
    int g = threadIdx.x >> 5;
    int c = threadIdx.x & 31;
    int d = blockIdx.x * 8 + g;
    bool act = d < N;
    float dd = 0.f, h3 = 0.f;
    if (act) {
        float acc = bfu(XWp[(size_t)d * D32 + c]);
        int p0 = rowptr[d], p1 = rowptr[d + 1];
        if (p1 > p0) {
            int pl = p1 - 1;
            unsigned short uA = XWp[(size_t)CLD(p0, 0) * D32 + c];
            unsigned short uB = XWp[(size_t)CLD(p0, 1) * D32 + c];
            unsigned short uC = XWp[(size_t)CLD(p0, 2) * D32 + c];
            unsigned short uD = XWp[(size_t)CLD(p0, 3) * D32 + c];
#pragma unroll 4
            for (int p = p0; p < p1; ++p) {
                unsigned short uN = XWp[(size_t)CLD(p, 4) * D32 + c];
                acc += bfu(uA);
                uA = uB; uB = uC; uC = uD; uD = uN;
            }
        }
        dd = DIS[d];
        h3 = dd * acc + bg[c];
    }
    float s = 0.f;
#pragma unroll
    for (int k = 0; k < 32; ++k)
        s = fmaf(__shfl(h3, k, 32), wgs[k * D32 + c], s);
    if (act) XWout[(size_t)d * D32 + c] = f2bf(dd * s);
}

// --- GCN layer 4 (final): gather bf16, fp32 out ----------------------------
__global__ __launch_bounds__(256) void k_gcn_last(
    const unsigned short* __restrict__ XWp, const float* __restrict__ DIS,
    const int* __restrict__ rowptr, const int* __restrict__ colsrc,
    const float* __restrict__ bg, float* __restrict__ Out, int N)
{
    int g = threadIdx.x >> 5;
    int c = threadIdx.x & 31;
    int d = blockIdx.x * 8 + g;
    if (d >= N) return;
    float acc = bfu(XWp[(size_t)d * D32 + c]);
    int p0 = rowptr[d], p1 = rowptr[d + 1];
    if (p1 > p0) {
        int pl = p1 - 1;
        unsigned short uA = XWp[(size_t)CLD(p0, 0) * D32 + c];
        unsigned short uB = XWp[(size_t)CLD(p0, 1) * D32 + c];
        unsigned short uC = XWp[(size_t)CLD(p0, 2) * D32 + c];
        unsigned short uD = XWp[(size_t)CLD(p0, 3) * D32 + c];
#pragma unroll 4
        for (int p = p0; p < p1; ++p) {
            unsigned short uN = XWp[(size_t)CLD(p, 4) * D32 + c];
            acc += bfu(uA);
            uA = uB; uB = uC; uC = uD; uD = uN;
        }
    }
    Out[(size_t)d * D32 + c] = DIS[d] * acc + bg[c];
}

// ---------------------------------------------------------------------------
extern "C" void kernel_launch(void* const* d_in, const int* in_sizes, int n_in,
                              void* d_out, int out_size, void* d_ws, size_t ws_size,
                              hipStream_t stream)
{
    const float* x  = (const float*)d_in[0];
    const int*   ei = (const int*)d_in[1];
    const int N = in_sizes[0] / INCH;
    const int E = in_sizes[1] / 2;
    const int* src = ei;
    const int* dst = ei + E;

    const float* W_embed = (const float*)d_in[2];
    const float* b_embed = (const float*)d_in[3];
    const float* Wg3 = (const float*)d_in[24];
    const float* bg3 = (const float*)d_in[25];
    const float* Wg4 = (const float*)d_in[26];
    const float* bg4 = (const float*)d_in[27];

    unsigned short* KV  = (unsigned short*)d_ws;        // N*512 bf16
    unsigned short* Qb  = KV + (size_t)N * 512;         // N*256 bf16
    float* H      = (float*)(Qb + (size_t)N * HCH);     // N*32 f32
    float* SKIP   = H + (size_t)N * D32;                // N*32 f32
    unsigned short* XW1 = (unsigned short*)(SKIP + (size_t)N * D32);  // N*32 bf16
    unsigned short* XW2 = XW1 + (size_t)N * D32;        // N*32 bf16
    int*   rowptr = (int*)(XW2 + (size_t)N * D32);      // N+1
    int*   colsrc = rowptr + (N + 1);                   // E
    int*   cursor = colsrc + E;                         // N
    int*   partials = cursor + N;                       // 256
    float* DIS    = (float*)(partials + 256);           // N
    float* WCB    = DIS + N;                            // 2*1056
    float* out    = (float*)d_out;

    const int nb8 = (N + 7) / 8;
    const int nbN = (N + 255) / 256;
    const int nbE = (E + 255) / 256;

    hipMemsetAsync(cursor, 0, (size_t)N * sizeof(int), stream);

    k_embed<<<nb8 + 2 + nbE, 256, 0, stream>>>(
        x, W_embed, b_embed, H, N, nb8, E, dst, cursor,
        (const float*)d_in[10], (const float*)d_in[11],
        (const float*)d_in[12], (const float*)d_in[13],
        (const float*)d_in[20], (const float*)d_in[21],
        (const float*)d_in[22], (const float*)d_in[23], WCB);

    k_scan1<<<nbN, 256, 0, stream>>>(cursor, rowptr, partials, DIS, N);
    k_scan2<<<1, 256, 0, stream>>>(partials, nbN);
    k_scan3b<<<nbN, 256, 0, stream>>>(rowptr, partials, cursor, N);
    k_fill<<<nbE, 256, 0, stream>>>(src, dst, cursor, colsrc, E);

    for (int layer = 0; layer < 2; ++layer) {
        int base = 4 + layer * 10;
        const float* Wq = (const float*)d_in[base + 0];
        const float* bq = (const float*)d_in[base + 1];
        const float* Wk = (const float*)d_in[base + 2];
        const float* bk = (const float*)d_in[base + 3];
        const float* Wv = (const float*)d_in[base + 4];
        const float* bv = (const float*)d_in[base + 5];
        const float* Wh = (const float*)d_in[base + 8];

        k_h32_to_kvqs<<<nb8, 256, 0, stream>>>(
            H, Wq, bq, Wk, bk, Wv, bv, WCB + layer * 1056, Qb, KV, SKIP, N);
        k_attn<<<(N + 3) / 4, 256, 0, stream>>>(
            (const uint4*)KV, (const uint2*)Qb, SKIP, H, rowptr, colsrc, Wh, N);
    }

    // XW3 = DIS * (H @ Wg3) in bf16, then GCN gathers
    k_xw3<<<nb8, 256, 0, stream>>>(H, Wg3, DIS, XW1, N);
    k_gcn_f<<<nb8, 256, 0, stream>>>(XW1, DIS, rowptr, colsrc, bg3, Wg4, XW2, N);
    k_gcn_last<<<nb8, 256, 0, stream>>>(XW2, DIS, rowptr, colsrc, bg4, out, N);
}